// Round 3
// baseline (67.097 us; speedup 1.0000x reference)
//
#include <hip/hip_runtime.h>
#include <math.h>

constexpr int QSP_DEPTH = 27;
constexpr int NPHI  = 2 * QSP_DEPTH + 1;   // 55 phis
constexpr int NSTEP = NPHI - 1;            // 54 W*S steps
constexpr int NC    = NSTEP / 2 + 1;       // 28 cosine-series coefficients
constexpr int NB    = 512;                 // 512 blocks * 256 thr * 4 elem = 2^19 = B

// v3: barrier-free, LDS-free single kernel.
//
// Every WAVE redundantly computes the 28 cosine-series coefficients of
// f(theta) = Re(<0|U|0>) (degree-27 series in 2*theta, established by the
// harness-verified v2.1):
//   - lanes 0..53 hold (cos,sin) of phi_{s+1}; broadcast per step via
//     v_readlane (compile-time lane index after unroll) -- no LDS, no shfl.
//   - lane k (<28) runs the 54-step SU(2) row-product at Chebyshev-Gauss
//     node theta_k = pi*(2k+1)/112 (8 FMAs/step, depth ~3).
//   - 28-point DCT-III (exact: l+m <= 54 < 56) via readlane(f,k) + hardware
//     v_cos on exact integer-mod-112 revolutions.
//   - coefficients redistributed via readlane -> SGPR-resident, freeing VGPRs.
// No __shared__, no __syncthreads, single dispatch: removes every
// serialization structure the v2.1 profile could have been paying for.
//
// Phase 2 (verified): Clenshaw on y = cos(2 theta), one float4 per thread;
// loads prefetched first so HBM latency hides under the coefficient prologue.
__device__ __forceinline__ float rl(float v, int l) {
    return __int_as_float(__builtin_amdgcn_readlane(__float_as_int(v), l));
}

__global__ __launch_bounds__(256) void qsp_fused_kernel(
    const float* __restrict__ x,
    const float* __restrict__ phis,
    const float* __restrict__ alphas,
    const float* __restrict__ bias,
    float* __restrict__ out, int n)
{
    const int t    = threadIdx.x;
    const int lane = t & 63;
    const int i    = blockIdx.x * 256 + t;    // one float4 per thread, exact cover
    const int nv   = n >> 2;
    const bool live = (i < nv);

    // ---- prefetch (consumed only in the epilogue; latency hides under prologue) ----
    float4 xv = make_float4(0.f, 0.f, 0.f, 0.f);
    float4 av = make_float4(0.f, 0.f, 0.f, 0.f);
    if (live) {
        xv = ((const float4*)x)[i];
        av = ((const float4*)alphas)[i];
    }
    const float b0 = bias[0];

    // per-lane step phases: lane s holds (cos,sin) of phi_{s+1}, s = 0..53.
    // clamp keeps lanes 54..63 in-bounds (values unused).
    const int sidx = (lane < NSTEP) ? (lane + 1) : NSTEP;
    float sph, cph;
    sincosf(phis[sidx], &sph, &cph);
    float s0, c0;
    sincosf(phis[0], &s0, &c0);

    // lane k: evaluate f at Chebyshev-Gauss node theta_k = pi*(2k+1)/112
    // (only k < 28 consumed; higher lanes compute harmlessly).
    const float theta = ((float)M_PI / 112.0f) * (float)(2 * lane + 1);
    float sth, cth;
    sincosf(theta, &sth, &cth);
    float ur = 1.f, ui = 0.f, vr = 0.f, vi = 0.f;
#pragma unroll
    for (int s = 0; s < NSTEP; ++s) {
        const float pc = rl(cph, s);                 // v_readlane -> wave-uniform
        const float ps = rl(sph, s);
        const float ar = fmaf(cth, ur, -sth * vi);   // a = c*u + i*s*v
        const float ai = fmaf(cth, ui,  sth * vr);
        const float br = fmaf(cth, vr, -sth * ui);   // b = i*s*u + c*v
        const float bi = fmaf(cth, vi,  sth * ur);
        ur = fmaf(pc, ar, -ps * ai);                 // u' = e^{+i phi} * a
        ui = fmaf(pc, ai,  ps * ar);
        vr = fmaf(pc, br,  ps * bi);                 // v' = e^{-i phi} * b
        vi = fmaf(pc, bi, -ps * br);
    }
    const float f = fmaf(c0, ur, -s0 * ui);          // f_k = Re(e^{i phi0} u), lane k

    // DCT-III: c_l = (l?2:1)/28 * sum_k f_k cos(2pi * l*(2k+1)/112)
    // angle tracked as exact integer m = l*(2k+1) mod 112, hardware v_cos on
    // revolutions (validated on HW by v2.1's pass). Lanes >= 28: garbage, unused.
    float acc = 0.f;
    int m = lane;
    const int step = 2 * lane;
#pragma unroll
    for (int k = 0; k < NC; ++k) {
        acc = fmaf(rl(f, k), __builtin_amdgcn_cosf((float)m * (1.0f / 112.0f)), acc);
        m += step;
        if (m >= 112) m -= 112;
    }
    const float csl = ((lane == 0) ? 1.f : 2.f) * (1.0f / 28.0f) * acc;

    // redistribute: all-literal readlanes -> coefficients live in SGPRs
    float c[NC];
#pragma unroll
    for (int l = 0; l < NC; ++l) c[l] = rl(csl, l);

    if (!live) return;

    float4 ov;
    const float* xe = (const float*)&xv;
    const float* ae = (const float*)&av;
    float* oe = (float*)&ov;
#pragma unroll
    for (int e = 0; e < 4; ++e) {
        const float y  = __cosf(2.0f * xe[e]);       // |2 theta| small; huge margin
        const float y2 = 2.0f * y;
        float b1 = 0.f, b2 = 0.f;
#pragma unroll
        for (int l = NC - 1; l >= 1; --l) {
            const float bl = fmaf(y2, b1, c[l] - b2);
            b2 = b1; b1 = bl;
        }
        oe[e] = fmaf(ae[e], fmaf(y, b1, c[0] - b2), b0);
    }
    ((float4*)out)[i] = ov;
}

extern "C" void kernel_launch(void* const* d_in, const int* in_sizes, int n_in,
                              void* d_out, int out_size, void* d_ws, size_t ws_size,
                              hipStream_t stream) {
    const float* x      = (const float*)d_in[0];
    const float* phis   = (const float*)d_in[1];
    const float* alphas = (const float*)d_in[2];
    const float* bias   = (const float*)d_in[3];
    float* out          = (float*)d_out;

    const int n = in_sizes[0];             // B = 524288
    qsp_fused_kernel<<<NB, 256, 0, stream>>>(x, phis, alphas, bias, out, n);
}

// Round 4
// 65.095 us; speedup vs baseline: 1.0308x; 1.0308x over previous
//
#include <hip/hip_runtime.h>
#include <math.h>

constexpr int QSP_DEPTH = 27;
constexpr int NPHI  = 2 * QSP_DEPTH + 1;   // 55 phis
constexpr int NSTEP = NPHI - 1;            // 54 W*S steps
constexpr int NC    = NSTEP / 2 + 1;       // 28 cosine-series coefficients
constexpr int NB    = 512;                 // 512 blocks * 256 thr * 4 elem = 2^19 = B

// v2.1 (replicate of the best-measured variant, 65.3 us in Round 2).
//
// Structural A/B/C across rounds showed total time is kernel-insensitive
// (v1 shuffle-chain 67.7, v2.1 LDS+barriers 65.3, v3 barrier-free 67.1):
// the measurement is dominated by the harness's 268 MB workspace poison-fill
// (41 us at 82% HBM peak -- its own roofline) plus ~21 us dispatch overhead.
// Kernel itself ~3-5 us vs a 1 us traffic floor; remaining slack < noise.
//
// Phase 1 (wave 0 of each block, redundant per block, no cross-lane ops):
// f(theta) = Re(<0|U|0>) is a degree-27 cosine series in 2*theta. Lane k
// (k<28) evaluates f at Chebyshev-Gauss node theta_k = pi*(2k+1)/112 via the
// 54-step SU(2) row-product (8 FMAs/step, phases broadcast from LDS); a
// 28-point DCT-III (exact: l+m <= 54 < 56) recovers the coefficients, with
// hardware v_cos on exact integer-mod-112 revolutions.
//
// Phase 2: Clenshaw on y = cos(2 theta), one float4 per thread; loads
// prefetched before phase 1 so HBM latency hides under it. cs[] staged
// LDS->registers with static indexing (28 ds_read_b32, reused 4x).
__global__ __launch_bounds__(256) void qsp_fused_kernel(
    const float* __restrict__ x,
    const float* __restrict__ phis,
    const float* __restrict__ alphas,
    const float* __restrict__ bias,
    float* __restrict__ out, int n)
{
    __shared__ float2 wph[NSTEP];   // (cos phi_k, sin phi_k), k = 1..54
    __shared__ float  fk[NC];       // f(theta_k) at the 28 Chebyshev nodes
    __shared__ float  cs[NC];       // cosine-series coefficients

    const int t = threadIdx.x;
    const int i = blockIdx.x * 256 + t;       // one float4 per thread, exact cover
    const int nv = n >> 2;
    const bool live = (i < nv);

    // ---- prefetch (consumed after the last barrier; latency hides under phase 1) ----
    float4 xv = make_float4(0.f, 0.f, 0.f, 0.f);
    float4 av = make_float4(0.f, 0.f, 0.f, 0.f);
    if (live) {
        xv = ((const float4*)x)[i];
        av = ((const float4*)alphas)[i];
    }
    const float b0 = bias[0];

    if (t < NSTEP) {
        float s, c;
        sincosf(phis[t + 1], &s, &c);
        wph[t] = make_float2(c, s);
    }
    __syncthreads();

    if (t < NC) {
        // theta_k = pi*(2k+1)/112 ; psi_k = 2*theta_k are the N=28 DCT-II nodes.
        const float theta = ((float)M_PI / 112.0f) * (float)(2 * t + 1);
        float sth, cth;
        sincosf(theta, &sth, &cth);
        float ur = 1.f, ui = 0.f, vr = 0.f, vi = 0.f;
#pragma unroll
        for (int s = 0; s < NSTEP; ++s) {
            const float2 p = wph[s];               // wave-uniform LDS broadcast
            const float ar = fmaf(cth, ur, -sth * vi);   // a = c*u + i*s*v
            const float ai = fmaf(cth, ui,  sth * vr);
            const float br = fmaf(cth, vr, -sth * ui);   // b = i*s*u + c*v
            const float bi = fmaf(cth, vi,  sth * ur);
            ur = fmaf(p.x, ar, -p.y * ai);               // u' = e^{+i phi} * a
            ui = fmaf(p.x, ai,  p.y * ar);
            vr = fmaf(p.x, br,  p.y * bi);               // v' = e^{-i phi} * b
            vi = fmaf(p.x, bi, -p.y * br);
        }
        float s0, c0;
        sincosf(phis[0], &s0, &c0);
        fk[t] = fmaf(c0, ur, -s0 * ui);          // f_k = Re(e^{i phi0} u)
    }
    __syncthreads();

    if (t < NC) {
        // c_t = (t?2:1)/28 * sum_k f_k cos(pi * t * (2k+1) / 56)
        // angle in revolutions = t*(2k+1)/112 ; track m = t*(2k+1) mod 112 exactly.
        float acc = 0.f;
        int m = t;
        const int step = 2 * t;
#pragma unroll
        for (int k = 0; k < NC; ++k) {
            acc = fmaf(fk[k], __builtin_amdgcn_cosf((float)m * (1.0f / 112.0f)), acc);
            m += step;
            if (m >= 112) m -= 112;               // m < 224 always: one subtract suffices
        }
        cs[t] = ((t == 0) ? 1.f : 2.f) * (1.0f / 28.0f) * acc;
    }
    __syncthreads();

    if (!live) return;

    // ---- stage coefficients into registers (static indices -> VGPRs, not scratch) ----
    float c[NC];
#pragma unroll
    for (int l = 0; l < NC; ++l) c[l] = cs[l];    // 28 wave-broadcast ds_read_b32

    float4 ov;
    const float* xe = (const float*)&xv;
    const float* ae = (const float*)&av;
    float* oe = (float*)&ov;
#pragma unroll
    for (int e = 0; e < 4; ++e) {
        const float y  = __cosf(2.0f * xe[e]);         // |2 theta| small; huge margin
        const float y2 = 2.0f * y;
        float b1 = 0.f, b2 = 0.f;
#pragma unroll
        for (int l = NC - 1; l >= 1; --l) {
            const float bl = fmaf(y2, b1, c[l] - b2);
            b2 = b1; b1 = bl;
        }
        oe[e] = fmaf(ae[e], fmaf(y, b1, c[0] - b2), b0);
    }
    ((float4*)out)[i] = ov;
}

extern "C" void kernel_launch(void* const* d_in, const int* in_sizes, int n_in,
                              void* d_out, int out_size, void* d_ws, size_t ws_size,
                              hipStream_t stream) {
    const float* x      = (const float*)d_in[0];
    const float* phis   = (const float*)d_in[1];
    const float* alphas = (const float*)d_in[2];
    const float* bias   = (const float*)d_in[3];
    float* out          = (float*)d_out;

    const int n = in_sizes[0];             // B = 524288
    qsp_fused_kernel<<<NB, 256, 0, stream>>>(x, phis, alphas, bias, out, n);
}